// Round 1
// baseline (334.562 us; speedup 1.0000x reference)
//
#include <hip/hip_runtime.h>

// GAE backward scan: gae[t] = delta[t] + coef[t]*gae[t+1], gae[T] = 0
//   delta[t] = reward[t] + GAMMA*next_value[t]*not_done[t] - value[t]
//   coef[t]  = GAMMA*LMBDA*not_done[t]
// advantages = gae; returns = gae + value.
// Parallelized as an associative scan over affine maps f(x) = A + P*x.
//
// R1: outputs stored with __builtin_nontemporal_store (evict-first in L2/L3).
// Rationale: inputs are 256 MiB == L3 size; output store-allocations were
// evicting input lines (FETCH_SIZE showed only ~50% input L3 hit). NT stores
// keep L3 for the read-once-per-dispatch, reused-across-iterations inputs.

#define GAMMA 0.99f
#define LMBDA 0.95f

constexpr int T_LEN      = 2048;
constexpr int PER_THREAD = 8;                  // time steps per thread
constexpr int BLOCK      = T_LEN / PER_THREAD; // 256 threads

typedef float f32x4 __attribute__((ext_vector_type(4)));

__global__ __launch_bounds__(BLOCK) void gae_kernel(
    const float* __restrict__ reward,
    const int*   __restrict__ terminated,
    const float* __restrict__ value,
    const float* __restrict__ next_value,
    float* __restrict__ adv_out,
    float* __restrict__ ret_out)
{
    const int b   = blockIdx.x;
    const int j   = threadIdx.x;
    const size_t base = (size_t)b * T_LEN + (size_t)j * PER_THREAD;

    // ---- coalesced vector loads: each thread owns 8 contiguous time steps
    const float4* r4  = (const float4*)(reward     + base);
    const float4* v4  = (const float4*)(value      + base);
    const float4* n4  = (const float4*)(next_value + base);
    const int4*   t4  = (const int4*)  (terminated + base);

    float4 r0 = r4[0], r1 = r4[1];
    float4 v0 = v4[0], v1 = v4[1];
    float4 n0 = n4[0], n1 = n4[1];
    int4   tA = t4[0], tB = t4[1];

    float rr[8] = {r0.x, r0.y, r0.z, r0.w, r1.x, r1.y, r1.z, r1.w};
    float vv[8] = {v0.x, v0.y, v0.z, v0.w, v1.x, v1.y, v1.z, v1.w};
    float nn[8] = {n0.x, n0.y, n0.z, n0.w, n1.x, n1.y, n1.z, n1.w};
    int   tt[8] = {tA.x, tA.y, tA.z, tA.w, tB.x, tB.y, tB.z, tB.w};

    float delta[8], coef[8];
#pragma unroll
    for (int i = 0; i < 8; ++i) {
        float nd = tt[i] ? 0.0f : 1.0f;
        delta[i] = rr[i] + GAMMA * nn[i] * nd - vv[i];
        coef[i]  = (GAMMA * LMBDA) * nd;
    }

    // ---- per-thread chunk summary: gae_at_chunk_start = A + P * gae_in_from_right
    float A = 0.0f, P = 1.0f;
#pragma unroll
    for (int i = 7; i >= 0; --i) {
        A = delta[i] + coef[i] * A;
        P = coef[i] * P;
    }

    // ---- wave-level backward inclusive scan (affine composition, 6 shfl steps)
    const int lane = j & 63;
    const int wave = j >> 6;
    float SA = A, SP = P;
#pragma unroll
    for (int o = 1; o < 64; o <<= 1) {
        float A2 = __shfl_down(SA, o, 64);
        float P2 = __shfl_down(SP, o, 64);
        if (lane + o < 64) {          // lanes past the end contribute identity
            SA = SA + SP * A2;
            SP = SP * P2;
        }
    }
    // exclusive-from-right: what enters this thread from lane+1
    float EA = __shfl_down(SA, 1, 64);
    float EP = __shfl_down(SP, 1, 64);
    if (lane == 63) { EA = 0.0f; EP = 1.0f; }

    // ---- combine the 4 wave summaries through LDS
    __shared__ float wA[BLOCK / 64];
    __shared__ float wP[BLOCK / 64];
    if (lane == 0) { wA[wave] = SA; wP[wave] = SP; }
    __syncthreads();

    // gae entering this wave from the right = (W_{wave+1} o ... o W_3)(0)
    float accA = 0.0f;
    for (int ww = (BLOCK / 64) - 1; ww > wave; --ww) {
        accA = wA[ww] + wP[ww] * accA;
    }

    // gae entering this thread from the right
    float g = EA + EP * accA;

    // ---- replay the chunk with the true incoming gae; write outputs
    float adv[8];
#pragma unroll
    for (int i = 7; i >= 0; --i) {
        g = delta[i] + coef[i] * g;
        adv[i] = g;
    }

    f32x4 a0 = {adv[0], adv[1], adv[2], adv[3]};
    f32x4 a1 = {adv[4], adv[5], adv[6], adv[7]};
    f32x4 q0 = {adv[0] + vv[0], adv[1] + vv[1], adv[2] + vv[2], adv[3] + vv[3]};
    f32x4 q1 = {adv[4] + vv[4], adv[5] + vv[5], adv[6] + vv[6], adv[7] + vv[7]};

    // Non-temporal: outputs are write-once, never re-read in this dispatch.
    // Keep them from evicting the (exactly L3-sized) input set.
    __builtin_nontemporal_store(a0, (f32x4*)(adv_out + base));
    __builtin_nontemporal_store(a1, (f32x4*)(adv_out + base + 4));
    __builtin_nontemporal_store(q0, (f32x4*)(ret_out + base));
    __builtin_nontemporal_store(q1, (f32x4*)(ret_out + base + 4));
}

extern "C" void kernel_launch(void* const* d_in, const int* in_sizes, int n_in,
                              void* d_out, int out_size, void* d_ws, size_t ws_size,
                              hipStream_t stream) {
    const float* reward     = (const float*)d_in[0];
    const int*   terminated = (const int*)  d_in[1];
    const float* value      = (const float*)d_in[2];
    const float* next_value = (const float*)d_in[3];

    const int total = in_sizes[0];          // B * T
    const int B     = total / T_LEN;        // T fixed at 2048 per setup_inputs()

    float* adv = (float*)d_out;             // outputs concatenated: [advantages | returns]
    float* ret = (float*)d_out + (size_t)total;

    gae_kernel<<<B, BLOCK, 0, stream>>>(reward, terminated, value, next_value, adv, ret);
}

// Round 2
// 314.772 us; speedup vs baseline: 1.0629x; 1.0629x over previous
//
#include <hip/hip_runtime.h>

// GAE backward scan: gae[t] = delta[t] + coef[t]*gae[t+1], gae[T] = 0
//   delta[t] = reward[t] + GAMMA*next_value[t]*not_done[t] - value[t]
//   coef[t]  = GAMMA*LMBDA*not_done[t]
// advantages = gae; returns = gae + value.
// Associative scan over affine maps f(x) = A + P*x.
//
// R2: revert NT stores (R1: WRITE_SIZE +23MB, dur +25us — nt defeats TCC
// write coalescing). New lever: 2 rows per block to test the latency-vs-
// bandwidth question. 16 loads in flight per thread (2x MLP), two
// interleaved shfl scans (2x ILP on the dependent chain), ONE barrier for
// both rows, half the blocks. Traffic unchanged.

#define GAMMA 0.99f
#define LMBDA 0.95f

constexpr int T_LEN      = 2048;
constexpr int PER_THREAD = 8;                  // time steps per thread
constexpr int BLOCK      = T_LEN / PER_THREAD; // 256 threads
constexpr int ROWS       = 2;                  // batch rows per block
constexpr int NWAVE      = BLOCK / 64;         // 4

__global__ __launch_bounds__(BLOCK) void gae_kernel(
    const float* __restrict__ reward,
    const int*   __restrict__ terminated,
    const float* __restrict__ value,
    const float* __restrict__ next_value,
    float* __restrict__ adv_out,
    float* __restrict__ ret_out,
    int nrows)
{
    const int j    = threadIdx.x;
    const int lane = j & 63;
    const int wave = j >> 6;
    const int row0 = blockIdx.x * ROWS;

    // ---- issue ALL loads for both rows up-front (16x dwordx4 in flight)
    float4 R[ROWS][2], V[ROWS][2], N[ROWS][2];
    int4   Tm[ROWS][2];
    size_t base[ROWS];
#pragma unroll
    for (int q = 0; q < ROWS; ++q) {
        int row = row0 + q;
        if (row >= nrows) row = row0;          // odd-B tail: duplicate row0 (benign)
        base[q] = (size_t)row * T_LEN + (size_t)j * PER_THREAD;
        const float4* r4 = (const float4*)(reward     + base[q]);
        const float4* v4 = (const float4*)(value      + base[q]);
        const float4* n4 = (const float4*)(next_value + base[q]);
        const int4*   t4 = (const int4*)  (terminated + base[q]);
        R[q][0] = r4[0]; R[q][1] = r4[1];
        V[q][0] = v4[0]; V[q][1] = v4[1];
        N[q][0] = n4[0]; N[q][1] = n4[1];
        Tm[q][0] = t4[0]; Tm[q][1] = t4[1];
    }

    // ---- delta/coef per row (frees R/N/Tm registers)
    float delta[ROWS][8], coef[ROWS][8], vv[ROWS][8];
#pragma unroll
    for (int q = 0; q < ROWS; ++q) {
        float rr[8] = {R[q][0].x, R[q][0].y, R[q][0].z, R[q][0].w,
                       R[q][1].x, R[q][1].y, R[q][1].z, R[q][1].w};
        float nn[8] = {N[q][0].x, N[q][0].y, N[q][0].z, N[q][0].w,
                       N[q][1].x, N[q][1].y, N[q][1].z, N[q][1].w};
        int   tt[8] = {Tm[q][0].x, Tm[q][0].y, Tm[q][0].z, Tm[q][0].w,
                       Tm[q][1].x, Tm[q][1].y, Tm[q][1].z, Tm[q][1].w};
        vv[q][0] = V[q][0].x; vv[q][1] = V[q][0].y; vv[q][2] = V[q][0].z; vv[q][3] = V[q][0].w;
        vv[q][4] = V[q][1].x; vv[q][5] = V[q][1].y; vv[q][6] = V[q][1].z; vv[q][7] = V[q][1].w;
#pragma unroll
        for (int i = 0; i < 8; ++i) {
            float nd = tt[i] ? 0.0f : 1.0f;
            delta[q][i] = rr[i] + GAMMA * nn[i] * nd - vv[q][i];
            coef[q][i]  = (GAMMA * LMBDA) * nd;
        }
    }

    // ---- per-thread chunk summary per row: start = A + P * gae_in_from_right
    float SA[ROWS], SP[ROWS];
#pragma unroll
    for (int q = 0; q < ROWS; ++q) {
        float A = 0.0f, P = 1.0f;
#pragma unroll
        for (int i = 7; i >= 0; --i) {
            A = delta[q][i] + coef[q][i] * A;
            P = coef[q][i] * P;
        }
        SA[q] = A; SP[q] = P;
    }

    // ---- wave-level backward inclusive scans, interleaved for ILP
#pragma unroll
    for (int o = 1; o < 64; o <<= 1) {
#pragma unroll
        for (int q = 0; q < ROWS; ++q) {
            float A2 = __shfl_down(SA[q], o, 64);
            float P2 = __shfl_down(SP[q], o, 64);
            if (lane + o < 64) {          // lanes past the end contribute identity
                SA[q] = SA[q] + SP[q] * A2;
                SP[q] = SP[q] * P2;
            }
        }
    }
    // exclusive-from-right per row
    float EA[ROWS], EP[ROWS];
#pragma unroll
    for (int q = 0; q < ROWS; ++q) {
        EA[q] = __shfl_down(SA[q], 1, 64);
        EP[q] = __shfl_down(SP[q], 1, 64);
        if (lane == 63) { EA[q] = 0.0f; EP[q] = 1.0f; }
    }

    // ---- combine the wave summaries for BOTH rows through one barrier
    __shared__ float wA[ROWS][NWAVE];
    __shared__ float wP[ROWS][NWAVE];
    if (lane == 0) {
#pragma unroll
        for (int q = 0; q < ROWS; ++q) { wA[q][wave] = SA[q]; wP[q][wave] = SP[q]; }
    }
    __syncthreads();

#pragma unroll
    for (int q = 0; q < ROWS; ++q) {
        // gae entering this wave from the right
        float accA = 0.0f;
        for (int ww = NWAVE - 1; ww > wave; --ww) {
            accA = wA[q][ww] + wP[q][ww] * accA;
        }
        // gae entering this thread from the right
        float g = EA[q] + EP[q] * accA;

        // replay the chunk with the true incoming gae
        float adv[8];
#pragma unroll
        for (int i = 7; i >= 0; --i) {
            g = delta[q][i] + coef[q][i] * g;
            adv[i] = g;
        }

        float4 a0 = {adv[0], adv[1], adv[2], adv[3]};
        float4 a1 = {adv[4], adv[5], adv[6], adv[7]};
        float4 q0 = {adv[0] + vv[q][0], adv[1] + vv[q][1], adv[2] + vv[q][2], adv[3] + vv[q][3]};
        float4 q1 = {adv[4] + vv[q][4], adv[5] + vv[q][5], adv[6] + vv[q][6], adv[7] + vv[q][7]};

        *(float4*)(adv_out + base[q])     = a0;
        *(float4*)(adv_out + base[q] + 4) = a1;
        *(float4*)(ret_out + base[q])     = q0;
        *(float4*)(ret_out + base[q] + 4) = q1;
    }
}

extern "C" void kernel_launch(void* const* d_in, const int* in_sizes, int n_in,
                              void* d_out, int out_size, void* d_ws, size_t ws_size,
                              hipStream_t stream) {
    const float* reward     = (const float*)d_in[0];
    const int*   terminated = (const int*)  d_in[1];
    const float* value      = (const float*)d_in[2];
    const float* next_value = (const float*)d_in[3];

    const int total = in_sizes[0];          // B * T
    const int B     = total / T_LEN;        // T fixed at 2048 per setup_inputs()

    float* adv = (float*)d_out;             // outputs concatenated: [advantages | returns]
    float* ret = (float*)d_out + (size_t)total;

    const int grid = (B + ROWS - 1) / ROWS;
    gae_kernel<<<grid, BLOCK, 0, stream>>>(reward, terminated, value, next_value, adv, ret, B);
}